// Round 1
// baseline (553.896 us; speedup 1.0000x reference)
//
#include <hip/hip_runtime.h>
#include <hip/hip_bf16.h>

#define NND 32768      // total nodes N = B*NNODES
#define NE  262144     // edges
#define NBAT 32
#define HD 128
#define IND 8
#define NPAIR 2048     // B*FEAS

__device__ __forceinline__ void fma4(float4& a, float s, const float4& w){
  a.x = fmaf(s, w.x, a.x);
  a.y = fmaf(s, w.y, a.y);
  a.z = fmaf(s, w.z, a.z);
  a.w = fmaf(s, w.w, a.w);
}
__device__ __forceinline__ float4 add4(float4 a, float4 b){
  a.x+=b.x; a.y+=b.y; a.z+=b.z; a.w+=b.w; return a;
}

// ---------------- CSR build ----------------
__global__ __launch_bounds__(256) void k_count(const int* __restrict__ dst, int* __restrict__ cnt){
  int e = blockIdx.x*256 + threadIdx.x;
  if (e < NE) atomicAdd(&cnt[dst[e]], 1);
}

__global__ __launch_bounds__(1024) void k_scan(const int* __restrict__ cnt, int* __restrict__ rowp,
                                               float* __restrict__ invdeg){
  __shared__ int part[1024];
  int t = threadIdx.x;
  int base = t*32;
  int local[32];
  int s = 0;
  #pragma unroll
  for (int j=0;j<32;j++){ local[j] = s; s += cnt[base+j]; }
  part[t] = s;
  __syncthreads();
  for (int d=1; d<1024; d<<=1){
    int v = (t>=d) ? part[t-d] : 0;
    __syncthreads();
    part[t] += v;
    __syncthreads();
  }
  int off = (t==0) ? 0 : part[t-1];
  #pragma unroll
  for (int j=0;j<32;j++){
    rowp[base+j] = off + local[j];
    int c = cnt[base+j];
    invdeg[base+j] = 1.0f / (float)(c > 0 ? c : 1);
  }
  if (t == 1023) rowp[NND] = off + s;
}

__global__ __launch_bounds__(256) void k_fill(const int* __restrict__ src, const int* __restrict__ dst,
                                              const int* __restrict__ rowp, int* __restrict__ fillc,
                                              int* __restrict__ csr){
  int e = blockIdx.x*256 + threadIdx.x;
  if (e < NE){
    int d = dst[e];
    int p = atomicAdd(&fillc[d], 1);
    csr[rowp[d] + p] = src[e];
  }
}

// ---------------- aggregation (mean over in-neighbors) ----------------
__global__ __launch_bounds__(256) void k_agg8(const float* __restrict__ x, const int* __restrict__ rowp,
                                              const int* __restrict__ csr, const float* __restrict__ invdeg,
                                              float* __restrict__ z8){
  int i = blockIdx.x*256 + threadIdx.x;
  float s[8] = {0,0,0,0,0,0,0,0};
  int a = rowp[i], bnd = rowp[i+1];
  for (int k=a;k<bnd;k++){
    int j = csr[k];
    const float4* p = (const float4*)&x[(size_t)j*8];
    float4 u0 = p[0], u1 = p[1];
    s[0]+=u0.x; s[1]+=u0.y; s[2]+=u0.z; s[3]+=u0.w;
    s[4]+=u1.x; s[5]+=u1.y; s[6]+=u1.z; s[7]+=u1.w;
  }
  float iv = invdeg[i];
  const float4* xp = (const float4*)&x[(size_t)i*8];
  float4 x0 = xp[0], x1 = xp[1];
  float4 o0, o1;
  o0.x = x0.x + s[0]*iv; o0.y = x0.y + s[1]*iv; o0.z = x0.z + s[2]*iv; o0.w = x0.w + s[3]*iv;
  o1.x = x1.x + s[4]*iv; o1.y = x1.y + s[5]*iv; o1.z = x1.z + s[6]*iv; o1.w = x1.w + s[7]*iv;
  ((float4*)&z8[(size_t)i*8])[0] = o0;
  ((float4*)&z8[(size_t)i*8])[1] = o1;
}

__global__ __launch_bounds__(128) void k_agg128(const float* __restrict__ h, const int* __restrict__ rowp,
                                                const int* __restrict__ csr, const float* __restrict__ invdeg,
                                                float* __restrict__ z){
  int i = blockIdx.x; int f = threadIdx.x;
  int a = rowp[i], bnd = rowp[i+1];
  float s = 0.0f;
  for (int k=a;k<bnd;k++){
    int j = csr[k];
    s += h[(size_t)j*HD + f];
  }
  z[(size_t)i*HD + f] = h[(size_t)i*HD + f] + s*invdeg[i];
}

// ---------------- GEMMs ----------------
// [nrows x 8] @ [8 x 128] + bias, ReLU
__global__ __launch_bounds__(256) void k_gemm8(const float* __restrict__ A, const float* __restrict__ W,
                                               const float* __restrict__ bias, float* __restrict__ C){
  __shared__ float Ws[IND*HD];
  __shared__ float bs[HD];
  int tid = threadIdx.x;
  for (int u=tid; u<IND*HD; u+=256) Ws[u] = W[u];
  if (tid < HD) bs[tid] = bias[tid];
  __syncthreads();
  int g = blockIdx.x*256 + tid;     // over NND*HD
  int row = g >> 7, c = g & 127;
  const float4* a4 = (const float4*)&A[(size_t)row*8];
  float4 a0 = a4[0], a1 = a4[1];
  float s = bs[c];
  s = fmaf(a0.x, Ws[0*128+c], s); s = fmaf(a0.y, Ws[1*128+c], s);
  s = fmaf(a0.z, Ws[2*128+c], s); s = fmaf(a0.w, Ws[3*128+c], s);
  s = fmaf(a1.x, Ws[4*128+c], s); s = fmaf(a1.y, Ws[5*128+c], s);
  s = fmaf(a1.z, Ws[6*128+c], s); s = fmaf(a1.w, Ws[7*128+c], s);
  C[g] = fmaxf(s, 0.0f);
}

// [nrows x K] @ [K x 128] + bias, ACT: 0 none, 1 relu, 2 tanh. nrows % 64 == 0.
// tile: 64 rows x 128 cols per block; thread = 4 rows x (4 + 4) cols.
template<int K, int ACT>
__global__ __launch_bounds__(256) void k_gemm(const float* __restrict__ A, const float* __restrict__ W,
                                              const float* __restrict__ bias, float* __restrict__ C){
  __shared__ float Ws[64*128];
  __shared__ float As[64*68];     // padded stride 68 to dodge bank conflicts
  int tid = threadIdx.x;
  int r0 = blockIdx.x * 64;
  int c0 = (tid & 15) * 4;        // cols c0..c0+3 and c0+64..c0+67
  int rg = tid >> 4;              // rows rg + 16*j
  float4 acc0[4], acc1[4];
  #pragma unroll
  for (int j=0;j<4;j++){ acc0[j] = make_float4(0,0,0,0); acc1[j] = make_float4(0,0,0,0); }
  for (int k0=0;k0<K;k0+=64){
    #pragma unroll
    for (int u=0;u<8;u++){
      int e = tid + u*256;
      int kk = e >> 5, cc = (e & 31) << 2;
      *(float4*)&Ws[kk*128+cc] = *(const float4*)&W[(size_t)(k0+kk)*128 + cc];
    }
    #pragma unroll
    for (int u=0;u<4;u++){
      int e = tid + u*256;
      int r = e >> 4, cc = (e & 15) << 2;
      *(float4*)&As[r*68+cc] = *(const float4*)&A[(size_t)(r0+r)*K + k0 + cc];
    }
    __syncthreads();
    #pragma unroll
    for (int kk=0; kk<64; kk+=4){
      float4 w0[4], w1[4];
      #pragma unroll
      for (int q=0;q<4;q++){
        w0[q] = *(const float4*)&Ws[(kk+q)*128 + c0];
        w1[q] = *(const float4*)&Ws[(kk+q)*128 + c0 + 64];
      }
      #pragma unroll
      for (int j=0;j<4;j++){
        float4 av = *(const float4*)&As[(rg + 16*j)*68 + kk];
        fma4(acc0[j], av.x, w0[0]); fma4(acc1[j], av.x, w1[0]);
        fma4(acc0[j], av.y, w0[1]); fma4(acc1[j], av.y, w1[1]);
        fma4(acc0[j], av.z, w0[2]); fma4(acc1[j], av.z, w1[2]);
        fma4(acc0[j], av.w, w0[3]); fma4(acc1[j], av.w, w1[3]);
      }
    }
    __syncthreads();
  }
  float4 bA = *(const float4*)&bias[c0];
  float4 bB = *(const float4*)&bias[c0+64];
  #pragma unroll
  for (int j=0;j<4;j++){
    int row = r0 + rg + 16*j;
    float4 v0 = add4(acc0[j], bA);
    float4 v1 = add4(acc1[j], bB);
    if (ACT == 1){
      v0.x = fmaxf(v0.x,0.f); v0.y = fmaxf(v0.y,0.f); v0.z = fmaxf(v0.z,0.f); v0.w = fmaxf(v0.w,0.f);
      v1.x = fmaxf(v1.x,0.f); v1.y = fmaxf(v1.y,0.f); v1.z = fmaxf(v1.z,0.f); v1.w = fmaxf(v1.w,0.f);
    } else if (ACT == 2){
      v0.x = tanhf(v0.x); v0.y = tanhf(v0.y); v0.z = tanhf(v0.z); v0.w = tanhf(v0.w);
      v1.x = tanhf(v1.x); v1.y = tanhf(v1.y); v1.z = tanhf(v1.z); v1.w = tanhf(v1.w);
    }
    *(float4*)&C[(size_t)row*HD + c0] = v0;
    *(float4*)&C[(size_t)row*HD + c0 + 64] = v1;
  }
}

// ---------------- BatchNorm ----------------
__global__ __launch_bounds__(128) void k_bn_stats(const float* __restrict__ Hraw, float* __restrict__ sum,
                                                  float* __restrict__ sqsum){
  int f = threadIdx.x;
  int r0 = blockIdx.x * 128;
  float s = 0.f, s2 = 0.f;
  for (int r=0;r<128;r++){
    float v = Hraw[(size_t)(r0+r)*HD + f];
    s += v; s2 = fmaf(v, v, s2);
  }
  atomicAdd(&sum[f], s);
  atomicAdd(&sqsum[f], s2);
}

__global__ __launch_bounds__(128) void k_bn_fin(const float* __restrict__ sum, const float* __restrict__ sq,
                                                const float* __restrict__ gamma, const float* __restrict__ beta,
                                                float* __restrict__ scale, float* __restrict__ shift){
  int f = threadIdx.x;
  float mu  = sum[f] * (1.0f/NND);
  float var = sq[f] * (1.0f/NND) - mu*mu;
  float sc  = gamma[f] * rsqrtf(var + 1e-5f);
  scale[f] = sc;
  shift[f] = beta[f] - mu*sc;
}

// bn apply + node_pool accumulate + per-batch gpool partial sums
__global__ __launch_bounds__(128) void k_bn_apply(const float* __restrict__ Hraw, const float* __restrict__ scale,
                                                  const float* __restrict__ shift, float* __restrict__ Hout,
                                                  float* __restrict__ npool, float* __restrict__ gsum, int first){
  int f = threadIdx.x;
  int r0 = blockIdx.x * 32;     // 32 rows per block, always within one batch (32 | 1024)
  int b = r0 >> 10;
  float sc = scale[f], sh = shift[f];
  float g = 0.f;
  for (int r=0;r<32;r++){
    size_t idx = (size_t)(r0+r)*HD + f;
    float v = fmaf(Hraw[idx], sc, sh);
    Hout[idx] = v;
    npool[idx] = first ? v : (npool[idx] + v);
    g += v;
  }
  atomicAdd(&gsum[b*HD + f], g);
}

// ---------------- policy on selected nodes only ----------------
__global__ __launch_bounds__(256) void k_build_aug(const int* __restrict__ mrows, const int* __restrict__ mcols,
                                                   const float* __restrict__ npool, const float* __restrict__ gsum,
                                                   float* __restrict__ aug){
  int idx = blockIdx.x;     // 0..4095: first 2048 = row nodes, next 2048 = col nodes
  int t = threadIdx.x;
  int j = idx & 2047;
  int rg = mrows[j];
  int b = rg >> 10;
  int g = (idx >= 2048) ? ((b << 10) | mcols[j]) : rg;
  float v;
  if (t < 128) v = npool[(size_t)g*HD + t];
  else         v = gsum[b*HD + (t-128)] * (1.0f/1024.0f);
  aug[(size_t)idx*256 + t] = v;
}

// score + per-batch sparse softmax (with dedup of repeated cells) + scatter
__global__ __launch_bounds__(64) void k_score(const float* __restrict__ Z, const int* __restrict__ mrows,
                                              const int* __restrict__ mcols, float* __restrict__ out){
  __shared__ int rr[64]; __shared__ int cc[64]; __shared__ float red[64];
  int b = blockIdx.x, f = threadIdx.x;
  int i = b*64 + f;
  int rg = mrows[i];
  int row = rg & 1023;
  int col = mcols[i];
  const float4* zr = (const float4*)&Z[(size_t)i*HD];
  const float4* zc = (const float4*)&Z[(size_t)(NPAIR + i)*HD];
  float s = 0.f;
  #pragma unroll
  for (int k=0;k<32;k++){
    float4 a = zr[k], c = zc[k];
    s = fmaf(a.x,c.x, fmaf(a.y,c.y, fmaf(a.z,c.z, fmaf(a.w,c.w, s))));
  }
  rr[f]=row; cc[f]=col; red[f]=s;
  __syncthreads();
  for (int d=32; d>0; d>>=1){
    if (f<d) red[f] = fmaxf(red[f], red[f+d]);
    __syncthreads();
  }
  float m = red[0];
  __syncthreads();
  bool first = true;
  for (int j=0;j<f;j++) if (rr[j]==row && cc[j]==col) first = false;
  float e = expf(s - m);
  red[f] = first ? e : 0.0f;
  __syncthreads();
  for (int d=32; d>0; d>>=1){
    if (f<d) red[f] += red[f+d];
    __syncthreads();
  }
  float denom = red[0];
  out[(size_t)b*1048576 + row*1024 + col] = e / denom;
}

extern "C" void kernel_launch(void* const* d_in, const int* in_sizes, int n_in,
                              void* d_out, int out_size, void* d_ws, size_t ws_size,
                              hipStream_t stream){
  const float* x     = (const float*)d_in[0];
  const int*   ei    = (const int*)d_in[1];
  // d_in[2] = batch_vec (structure is repeat(arange(B), 1024) — implied by indices)
  const int*   mrows = (const int*)d_in[3];
  const int*   mcols = (const int*)d_in[4];
  const float* g0w1  = (const float*)d_in[5];
  const float* g0b1  = (const float*)d_in[6];
  const float* g0w2  = (const float*)d_in[7];
  const float* g0b2  = (const float*)d_in[8];
  const float* gw1   = (const float*)d_in[9];
  const float* gb1   = (const float*)d_in[10];
  const float* gw2   = (const float*)d_in[11];
  const float* gb2   = (const float*)d_in[12];
  const float* bng   = (const float*)d_in[13];
  const float* bnb   = (const float*)d_in[14];
  const float* p0w1  = (const float*)d_in[15];
  const float* p0b1  = (const float*)d_in[16];
  const float* p0w2  = (const float*)d_in[17];
  const float* p0b2  = (const float*)d_in[18];
  const float* pw1   = (const float*)d_in[19];
  const float* pb1   = (const float*)d_in[20];
  const float* pw2   = (const float*)d_in[21];
  const float* pb2   = (const float*)d_in[22];

  // workspace layout (~70 MB)
  float* fw    = (float*)d_ws;
  float* h     = fw;                       // N*H
  float* zb    = fw + 4194304;             // N*H
  float* tb    = fw + 2*4194304;           // N*H
  float* npool = fw + 3*4194304;           // N*H
  float* z8    = fw + 4*4194304;           // N*8
  float* gsum  = z8 + 262144;              // B*H
  float* bnsum = gsum + 4096;              // H
  float* bnsq  = bnsum + 128;              // H
  float* bnsc  = bnsq + 128;               // H
  float* bnsh  = bnsc + 128;               // H
  float* invdeg= bnsh + 128;               // N
  int* cnt   = (int*)(invdeg + NND);       // N
  int* rowp  = cnt + NND;                  // N+1
  int* fillc = rowp + NND + 1;             // N
  int* csr   = fillc + NND;                // E
  float* aug = tb;                         // 4096*256 (reuse)
  float* pA  = zb;                         // 4096*128 (reuse)
  float* pB  = zb + 524288;                // 4096*128 (reuse)

  const int* src = ei;
  const int* dst = ei + NE;

  hipMemsetAsync(d_out, 0, (size_t)out_size*sizeof(float), stream);
  hipMemsetAsync(cnt, 0, NND*sizeof(int), stream);
  hipMemsetAsync(fillc, 0, NND*sizeof(int), stream);
  hipMemsetAsync(gsum, 0, 4096*sizeof(float), stream);

  hipLaunchKernelGGL(k_count, dim3(NE/256), dim3(256), 0, stream, dst, cnt);
  hipLaunchKernelGGL(k_scan, dim3(1), dim3(1024), 0, stream, cnt, rowp, invdeg);
  hipLaunchKernelGGL(k_fill, dim3(NE/256), dim3(256), 0, stream, src, dst, rowp, fillc, csr);

  // layer 0
  hipLaunchKernelGGL(k_agg8, dim3(NND/256), dim3(256), 0, stream, x, rowp, csr, invdeg, z8);
  hipLaunchKernelGGL(k_gemm8, dim3(NND*HD/256), dim3(256), 0, stream, z8, g0w1, g0b1, tb);
  hipLaunchKernelGGL((k_gemm<128,1>), dim3(NND/64), dim3(256), 0, stream, tb, g0w2, g0b2, zb);
  hipMemsetAsync(bnsum, 0, 256*sizeof(float), stream);
  hipLaunchKernelGGL(k_bn_stats, dim3(256), dim3(128), 0, stream, zb, bnsum, bnsq);
  hipLaunchKernelGGL(k_bn_fin, dim3(1), dim3(128), 0, stream, bnsum, bnsq, bng, bnb, bnsc, bnsh);
  hipLaunchKernelGGL(k_bn_apply, dim3(NND/32), dim3(128), 0, stream, zb, bnsc, bnsh, h, npool, gsum, 1);

  // layers 1..3
  for (int l=0;l<3;l++){
    hipLaunchKernelGGL(k_agg128, dim3(NND), dim3(128), 0, stream, h, rowp, csr, invdeg, zb);
    hipLaunchKernelGGL((k_gemm<128,1>), dim3(NND/64), dim3(256), 0, stream, zb, gw1 + l*16384, gb1 + l*128, tb);
    hipLaunchKernelGGL((k_gemm<128,1>), dim3(NND/64), dim3(256), 0, stream, tb, gw2 + l*16384, gb2 + l*128, zb);
    hipMemsetAsync(bnsum, 0, 256*sizeof(float), stream);
    hipLaunchKernelGGL(k_bn_stats, dim3(256), dim3(128), 0, stream, zb, bnsum, bnsq);
    hipLaunchKernelGGL(k_bn_fin, dim3(1), dim3(128), 0, stream, bnsum, bnsq, bng + (l+1)*128, bnb + (l+1)*128, bnsc, bnsh);
    hipLaunchKernelGGL(k_bn_apply, dim3(NND/32), dim3(128), 0, stream, zb, bnsc, bnsh, h, npool, gsum, 0);
  }

  // policy on the 4096 referenced node instances only
  hipLaunchKernelGGL(k_build_aug, dim3(4096), dim3(256), 0, stream, mrows, mcols, npool, gsum, aug);
  hipLaunchKernelGGL((k_gemm<256,2>), dim3(64), dim3(256), 0, stream, aug, p0w1, p0b1, pA);
  hipLaunchKernelGGL((k_gemm<128,0>), dim3(64), dim3(256), 0, stream, pA, p0w2, p0b2, pB);
  hipLaunchKernelGGL((k_gemm<128,2>), dim3(64), dim3(256), 0, stream, pB, pw1, pb1, pA);
  hipLaunchKernelGGL((k_gemm<128,0>), dim3(64), dim3(256), 0, stream, pA, pw2, pb2, pB);
  hipLaunchKernelGGL((k_gemm<128,2>), dim3(64), dim3(256), 0, stream, pB, pw1 + 16384, pb1 + 128, pA);
  hipLaunchKernelGGL((k_gemm<128,0>), dim3(64), dim3(256), 0, stream, pA, pw2 + 16384, pb2 + 128, pB);

  hipLaunchKernelGGL(k_score, dim3(32), dim3(64), 0, stream, pB, mrows, mcols, (float*)d_out);
}